// Round 1
// baseline (12723.326 us; speedup 1.0000x reference)
//
#include <hip/hip_runtime.h>
#include <stdint.h>

#define NB        64
#define NN        131072
#define NPTS      1024
#define WGS_PER_B 4
#define TPB       1024
#define PPT       (NN / WGS_PER_B / TPB)   // 32 points per thread

// Packed comparison key: max over (dist asc bits, then ~idx) == (max dist, min idx)
// dist >= 0 so float bits are order-preserving. Exactly matches jnp.argmax
// first-occurrence tie-break.

__global__ __launch_bounds__(TPB) void fps_kernel(
    const float* __restrict__ pos,
    const int*   __restrict__ start_p,
    int*         __restrict__ out,
    unsigned long long* __restrict__ slots)
{
#pragma clang fp contract(off)
    const int wg   = blockIdx.x;
    const int xcd  = wg & 7;          // assume round-robin blockIdx->XCD (perf heuristic only)
    const int sl   = wg >> 3;         // 0..31 slot within XCD
    const int b    = xcd * 8 + (sl >> 2);   // batch: 8 batches per XCD
    const int r    = sl & 3;                // rank within batch (0..3)
    const int t    = threadIdx.x;
    const int lane = t & 63;
    const int wv   = t >> 6;

    const float* P = pos + (size_t)b * (size_t)NN * 3u;
    unsigned long long* bslots = slots + (size_t)b * NPTS * WGS_PER_B;

    __shared__ float smp[3];
    __shared__ unsigned long long wred[TPB / 64];

    // Initialization: sample 0 is start_idx.
    if (t == 0) {
        const int start = start_p[0];
        const float* sp = P + (size_t)start * 3u;
        smp[0] = sp[0]; smp[1] = sp[1]; smp[2] = sp[2];
        if (r == 0) out[b * NPTS] = start;
    }
    __syncthreads();
    float sx = smp[0], sy = smp[1], sz = smp[2];

    // Per-thread running min-distance, fully register-resident (static indices).
    float dist[PPT];
#pragma unroll
    for (int j = 0; j < PPT; ++j) dist[j] = __builtin_inff();

    const int base = r * (NN / WGS_PER_B);

    for (int k = 1; k < NPTS; ++k) {
        float best = -1.0f;
        int   bidx = 0;
#pragma unroll
        for (int j = 0; j < PPT; ++j) {
            const int i = base + t + j * TPB;
            const float* pp = P + (size_t)i * 3u;
            const float px = pp[0], py = pp[1], pz = pp[2];
            const float dx = px - sx, dy = py - sy, dz = pz - sz;
            // contract(off): (dx*dx + dy*dy) + dz*dz, each op rounded — matches numpy.
            const float d  = (dx * dx + dy * dy) + dz * dz;
            const float nd = fminf(dist[j], d);
            dist[j] = nd;
            if (nd > best) { best = nd; bidx = i; }   // strict > keeps first (lowest) index
        }

        unsigned long long pk =
            ((unsigned long long)__float_as_uint(best) << 32) |
            (unsigned int)(~(unsigned int)bidx);

        // 64-lane wave max-reduce.
#pragma unroll
        for (int o = 32; o >= 1; o >>= 1) {
            const unsigned long long q = __shfl_xor(pk, o, 64);
            pk = (q > pk) ? q : pk;
        }
        if (lane == 0) wred[wv] = pk;
        __syncthreads();

        if (wv == 0) {
            unsigned long long v = (lane < (TPB / 64)) ? wred[lane] : 0ull;
#pragma unroll
            for (int o = 8; o >= 1; o >>= 1) {
                const unsigned long long q = __shfl_xor(v, o, 64);
                v = (q > v) ? q : v;
            }
            if (lane == 0) {
                __hip_atomic_store(&bslots[(size_t)k * WGS_PER_B + r], v,
                                   __ATOMIC_RELEASE, __HIP_MEMORY_SCOPE_AGENT);
            }
            // Lock-free join: 4 lanes spin on the 4 rank slots (nonzero == published;
            // any real packed value is nonzero since ~idx != 0).
            unsigned long long g = 0ull;
            if (lane < WGS_PER_B) {
                for (;;) {
                    g = __hip_atomic_load(&bslots[(size_t)k * WGS_PER_B + lane],
                                          __ATOMIC_ACQUIRE, __HIP_MEMORY_SCOPE_AGENT);
                    if (g != 0ull) break;
                    __builtin_amdgcn_s_sleep(1);
                }
            }
#pragma unroll
            for (int o = 2; o >= 1; o >>= 1) {
                const unsigned long long q = __shfl_xor(g, o, 64);
                g = (q > g) ? q : g;
            }
            if (lane == 0) {
                const int widx = (int)(~(unsigned int)g);
                const float* wp = P + (size_t)widx * 3u;
                smp[0] = wp[0]; smp[1] = wp[1]; smp[2] = wp[2];
                if (r == 0) out[b * NPTS + k] = widx;
            }
        }
        __syncthreads();
        sx = smp[0]; sy = smp[1]; sz = smp[2];
    }
}

extern "C" void kernel_launch(void* const* d_in, const int* in_sizes, int n_in,
                              void* d_out, int out_size, void* d_ws, size_t ws_size,
                              hipStream_t stream)
{
    const float* pos     = (const float*)d_in[0];
    const int*   start_p = (const int*)d_in[1];
    int*         out     = (int*)d_out;
    unsigned long long* slots = (unsigned long long*)d_ws;

    const size_t slot_bytes = (size_t)NB * NPTS * WGS_PER_B * sizeof(unsigned long long); // 2 MB
    hipMemsetAsync(d_ws, 0, slot_bytes, stream);

    void* args[] = { (void*)&pos, (void*)&start_p, (void*)&out, (void*)&slots };
    hipLaunchCooperativeKernel((const void*)fps_kernel,
                               dim3(NB * WGS_PER_B), dim3(TPB),
                               args, 0, stream);
}

// Round 3
// 4409.861 us; speedup vs baseline: 2.8852x; 2.8852x over previous
//
#include <hip/hip_runtime.h>
#include <stdint.h>

#define NB    64
#define NN    131072
#define NPTS  1024
#define WPB   4                    // workgroups per batch
#define TPB   512                  // 8 waves
#define NWAVE (TPB / 64)
#define CHUNK (NN / WPB)           // 32768 points per wg
#define PPT   (CHUNK / TPB)        // 64 points per thread
#define RPTS  38                   // register-resident points/thread
#define LPTS  10                   // LDS-resident points/thread (61440 B)
#define GPTS  16                   // L2-streamed points/thread
#define RPAIR (RPTS / 2)
#define LPAIR (LPTS / 2)
#define GPAIR (GPTS / 2)

typedef float v2f __attribute__((ext_vector_type(2)));
typedef unsigned long long u64;

// Packed key: [dist_bits:32 | ~idx:32] -> u64 max = (max dist, then min idx),
// exactly jnp.argmax first-occurrence tie-break. ~idx never 0, so slot!=0
// doubles as the publish flag (slots zeroed by memset each call).

__global__ __launch_bounds__(TPB) void fps_kernel(
    const float* __restrict__ pos,
    const int*   __restrict__ start_p,
    int*         __restrict__ out,
    u64*         __restrict__ slots)
{
#pragma clang fp contract(off)
    const int wg   = blockIdx.x;
    const int xcd  = wg & 7;            // heuristic: keep a batch's 4 wgs on one XCD
    const int sl   = wg >> 3;
    const int b    = xcd * 8 + (sl >> 2);
    const int r    = sl & 3;
    const int t    = threadIdx.x;
    const int lane = t & 63;
    const int wv   = t >> 6;

    const float* __restrict__ P  = pos + (size_t)b * NN * 3;
    const float* __restrict__ Pc = P + (size_t)r * CHUNK * 3;
    u64* __restrict__ bslots = slots + (size_t)b * NPTS * WPB;

    __shared__ float ldsP[LPTS * TPB * 3];     // 61440 B
    __shared__ u64   wred[2][NWAVE];           // banked by k&1 (one-barrier design)

    // ---- one-time staging: 38 pts -> regs, 10 pts -> LDS (own-thread only) ----
    v2f rx[RPAIR], ry[RPAIR], rz[RPAIR];
#pragma unroll
    for (int p = 0; p < RPAIR; ++p) {
        const float* a = Pc + (size_t)(t + (2 * p) * TPB) * 3;
        const float* c = a + (size_t)TPB * 3;
        rx[p] = (v2f){a[0], c[0]};
        ry[p] = (v2f){a[1], c[1]};
        rz[p] = (v2f){a[2], c[2]};
    }
#pragma unroll
    for (int j = 0; j < LPTS; ++j) {
        const float* a = Pc + (size_t)(t + (RPTS + j) * TPB) * 3;
        float* d = &ldsP[(size_t)(t + j * TPB) * 3];
        d[0] = a[0]; d[1] = a[1]; d[2] = a[2];   // same-thread RAW later: no barrier needed
    }

    const int start = start_p[0];
    float sx = P[(size_t)start * 3 + 0];
    float sy = P[(size_t)start * 3 + 1];
    float sz = P[(size_t)start * 3 + 2];
    if (r == 0 && t == 0) out[(size_t)b * NPTS] = start;

    v2f dist[PPT / 2];
#pragma unroll
    for (int p = 0; p < PPT / 2; ++p)
        dist[p] = (v2f){__builtin_inff(), __builtin_inff()};

    const int gbase = r * CHUNK;

    for (int k = 1; k < NPTS; ++k) {
        const v2f s0 = (v2f){sx, sx}, s1 = (v2f){sy, sy}, s2 = (v2f){sz, sz};
        float best = -1.0f;
        int   bi   = 0;

        v2f gx[GPAIR], gy[GPAIR], gz[GPAIR];
        // issue streamed batch A early (L2-resident addresses)
#pragma unroll
        for (int p = 0; p < 4; ++p) {
            const float* a = Pc + (size_t)(t + (RPTS + LPTS + 2 * p) * TPB) * 3;
            const float* c = a + (size_t)TPB * 3;
            gx[p] = (v2f){a[0], c[0]};
            gy[p] = (v2f){a[1], c[1]};
            gz[p] = (v2f){a[2], c[2]};
        }

        // exact per-op rounding: (dx*dx + dy*dy) + dz*dz, contract off
#define PAIR_STEP(DP, PX, PY, PZ, I0)                                    \
        {                                                                \
            v2f dx = (PX) - s0, dy = (PY) - s1, dz = (PZ) - s2;          \
            v2f d  = (dx * dx + dy * dy) + dz * dz;                      \
            v2f nd;                                                      \
            nd.x = fminf(dist[DP].x, d.x);                               \
            nd.y = fminf(dist[DP].y, d.y);                               \
            dist[DP] = nd;                                               \
            if (nd.x > best) { best = nd.x; bi = (I0); }                 \
            if (nd.y > best) { best = nd.y; bi = (I0) + TPB; }           \
        }

#pragma unroll
        for (int p = 0; p < RPAIR; ++p)
            PAIR_STEP(p, rx[p], ry[p], rz[p], gbase + t + (2 * p) * TPB);

        // issue streamed batch B (still ~100 insts before first use)
#pragma unroll
        for (int p = 4; p < GPAIR; ++p) {
            const float* a = Pc + (size_t)(t + (RPTS + LPTS + 2 * p) * TPB) * 3;
            const float* c = a + (size_t)TPB * 3;
            gx[p] = (v2f){a[0], c[0]};
            gy[p] = (v2f){a[1], c[1]};
            gz[p] = (v2f){a[2], c[2]};
        }

#pragma unroll
        for (int p = 0; p < LPAIR; ++p) {
            const int li0 = (t + (2 * p) * TPB) * 3;
            const int li1 = li0 + TPB * 3;
            v2f px = (v2f){ldsP[li0 + 0], ldsP[li1 + 0]};
            v2f py = (v2f){ldsP[li0 + 1], ldsP[li1 + 1]};
            v2f pz = (v2f){ldsP[li0 + 2], ldsP[li1 + 2]};
            PAIR_STEP(RPAIR + p, px, py, pz, gbase + t + (RPTS + 2 * p) * TPB);
        }
#pragma unroll
        for (int p = 0; p < GPAIR; ++p)
            PAIR_STEP(RPAIR + LPAIR + p, gx[p], gy[p], gz[p],
                      gbase + t + (RPTS + LPTS + 2 * p) * TPB);
#undef PAIR_STEP

        u64 pk = ((u64)__float_as_uint(best) << 32) | (unsigned)~bi;

#pragma unroll
        for (int o = 32; o >= 1; o >>= 1) {
            u64 q = __shfl_xor(pk, o, 64);
            if (q > pk) pk = q;
        }
        if (lane == 0) wred[k & 1][wv] = pk;
        __syncthreads();

        // every wave reduces the 8 wave-partials itself (no 2nd barrier)
        u64 v = wred[k & 1][lane & (NWAVE - 1)];
#pragma unroll
        for (int o = 1; o < NWAVE; o <<= 1) {
            u64 q = __shfl_xor(v, o, 64);
            if (q > v) v = q;
        }
        if (t == 0)
            __hip_atomic_store(&bslots[(size_t)k * WPB + r], v,
                               __ATOMIC_RELAXED, __HIP_MEMORY_SCOPE_AGENT);

        // all lanes spin: lane L polls slot (L&3); value-only communication,
        // relaxed is sufficient (payload is the atomic word itself)
        const u64* sp = &bslots[(size_t)k * WPB + (lane & (WPB - 1))];
        u64 g;
        for (;;) {
            g = __hip_atomic_load(sp, __ATOMIC_RELAXED, __HIP_MEMORY_SCOPE_AGENT);
            if (g) break;
            __builtin_amdgcn_s_sleep(1);
        }
#pragma unroll
        for (int o = 1; o < WPB; o <<= 1) {
            u64 q = __shfl_xor(g, o, 64);
            if (q > g) g = q;
        }
        const int widx = (int)~(unsigned)g;
        if (r == 0 && t == 0) out[(size_t)b * NPTS + k] = widx;
        sx = P[(size_t)widx * 3 + 0];
        sy = P[(size_t)widx * 3 + 1];
        sz = P[(size_t)widx * 3 + 2];
    }
}

extern "C" void kernel_launch(void* const* d_in, const int* in_sizes, int n_in,
                              void* d_out, int out_size, void* d_ws, size_t ws_size,
                              hipStream_t stream)
{
    const float* pos     = (const float*)d_in[0];
    const int*   start_p = (const int*)d_in[1];
    int*         out     = (int*)d_out;
    u64*         slots   = (u64*)d_ws;

    // 64 batches x 1024 rounds x 4 slots x 8 B = 2 MB
    hipMemsetAsync(d_ws, 0, (size_t)NB * NPTS * WPB * sizeof(u64), stream);

    void* args[] = { (void*)&pos, (void*)&start_p, (void*)&out, (void*)&slots };
    hipError_t e = hipLaunchCooperativeKernel((const void*)fps_kernel,
                                              dim3(NB * WPB), dim3(TPB),
                                              args, 0, stream);
    if (e != hipSuccess) {
        // 256 blocks of 512 thr = 1 block/CU: de-facto co-resident; same protocol.
        fps_kernel<<<dim3(NB * WPB), dim3(TPB), 0, stream>>>(pos, start_p, out, slots);
    }
}